// Round 1
// baseline (4944.681 us; speedup 1.0000x reference)
//
#include <hip/hip_runtime.h>
#include <math.h>

#define Tt 64
#define Bb 16
#define Nn 256
#define Ww 64
#define Rr 4
#define INd 64
#define OUTd 64
#define NH 256
#define NO 256
#define IFS 471
#define INDIM 320        // IN + R*W
#define EPSf 1e-6f

__device__ __forceinline__ float sigm(float x) { return 1.f / (1.f + expf(-x)); }
// jax.nn.softplus(x) = max(x,0) + log1p(exp(-|x|)); oneplus = 1 + softplus
__device__ __forceinline__ float oneplus_(float x) {
    return 1.f + fmaxf(x, 0.f) + log1pf(expf(-fabsf(x)));
}

__device__ __forceinline__ float bsum(float v, float* sred, int tid) {
#pragma unroll
    for (int o = 32; o; o >>= 1) v += __shfl_xor(v, o, 64);
    __syncthreads();
    if ((tid & 63) == 0) sred[tid >> 6] = v;
    __syncthreads();
    return (sred[0] + sred[1]) + (sred[2] + sred[3]);
}
__device__ __forceinline__ float bmax(float v, float* sred, int tid) {
#pragma unroll
    for (int o = 32; o; o >>= 1) v = fmaxf(v, __shfl_xor(v, o, 64));
    __syncthreads();
    if ((tid & 63) == 0) sred[tid >> 6] = v;
    __syncthreads();
    return fmaxf(fmaxf(sred[0], sred[1]), fmaxf(sred[2], sred[3]));
}
__device__ __forceinline__ float4 bsum4(float4 v, float* sred, int tid) {
#pragma unroll
    for (int o = 32; o; o >>= 1) {
        v.x += __shfl_xor(v.x, o, 64);
        v.y += __shfl_xor(v.y, o, 64);
        v.z += __shfl_xor(v.z, o, 64);
        v.w += __shfl_xor(v.w, o, 64);
    }
    __syncthreads();
    if ((tid & 63) == 0) {
        int p = (tid >> 6) * 4;
        sred[p] = v.x; sred[p + 1] = v.y; sred[p + 2] = v.z; sred[p + 3] = v.w;
    }
    __syncthreads();
    float4 r;
    r.x = (sred[0] + sred[4]) + (sred[8] + sred[12]);
    r.y = (sred[1] + sred[5]) + (sred[9] + sred[13]);
    r.z = (sred[2] + sred[6]) + (sred[10] + sred[14]);
    r.w = (sred[3] + sred[7]) + (sred[11] + sred[15]);
    return r;
}
__device__ __forceinline__ float4 bmax4(float4 v, float* sred, int tid) {
#pragma unroll
    for (int o = 32; o; o >>= 1) {
        v.x = fmaxf(v.x, __shfl_xor(v.x, o, 64));
        v.y = fmaxf(v.y, __shfl_xor(v.y, o, 64));
        v.z = fmaxf(v.z, __shfl_xor(v.z, o, 64));
        v.w = fmaxf(v.w, __shfl_xor(v.w, o, 64));
    }
    __syncthreads();
    if ((tid & 63) == 0) {
        int p = (tid >> 6) * 4;
        sred[p] = v.x; sred[p + 1] = v.y; sred[p + 2] = v.z; sred[p + 3] = v.w;
    }
    __syncthreads();
    float4 r;
    r.x = fmaxf(fmaxf(sred[0], sred[4]), fmaxf(sred[8], sred[12]));
    r.y = fmaxf(fmaxf(sred[1], sred[5]), fmaxf(sred[9], sred[13]));
    r.z = fmaxf(fmaxf(sred[2], sred[6]), fmaxf(sred[10], sred[14]));
    r.w = fmaxf(fmaxf(sred[3], sred[7]), fmaxf(sred[11], sred[15]));
    return r;
}

// One block per batch element; 256 threads (4 waves). Entire T=64 scan inside.
__global__ __launch_bounds__(256, 1) void dnc_kernel(
    const float* __restrict__ x,     // (T,B,IN)
    const float* __restrict__ W1,    // (320,256)
    const float* __restrict__ b1,    // (256)
    const float* __restrict__ W2,    // (256,256)
    const float* __restrict__ b2,    // (256)
    const float* __restrict__ Wif,   // (256,471)
    const float* __restrict__ bif,   // (471)
    const float* __restrict__ Wout,  // (256,64)
    const float* __restrict__ Wmem,  // (256,64)
    float* __restrict__ out,         // (T,B,64)
    float* __restrict__ ws)
{
    const int b = blockIdx.x;
    const int tid = threadIdx.x;

    // workspace: per-batch mem transposed [w][n], link [n][m]
    float* memT = ws + (size_t)b * (Ww * Nn);
    float* link = ws + (size_t)Bb * (Ww * Nn) + (size_t)b * (Nn * Nn);

    __shared__ float s_ctrl[INDIM];
    __shared__ float s_h[NH];
    __shared__ float s_nn[NO];
    __shared__ float s_z[IFS + 1];
    __shared__ float s_usage[Nn];
    __shared__ float s_ww[Nn];
    __shared__ float s_prec[Nn];
    __shared__ float s_alloc[Nn];
    __shared__ float s_rw[Nn][Rr];       // read weights (16B rows)
    __shared__ float s_rvec[Ww][Rr];     // rvec[w][r], flat == w*R+r
    __shared__ float s_skey[Nn];
    __shared__ int   s_sidx[Nn];
    __shared__ float s_cp[Nn];
    __shared__ float s_rkeyn[Ww][Rr];    // normalized read keys
    __shared__ float s_wkeyn[Ww];        // normalized write key
    __shared__ float s_erase[Ww];
    __shared__ float s_wvec[Ww];
    __shared__ float s_fg[Rr];
    __shared__ float s_rstr[Rr];
    __shared__ float s_knorm[Rr];
    __shared__ float s_rmode[3][Rr];
    __shared__ float s_outp[4][OUTd];
    __shared__ float s_red[16];
    __shared__ float s_sc[4];            // 0:write_str 1:alloc_gate 2:write_gate 3:wkey_norm

    // ---- init state (ws is poisoned before every launch) ----
    for (int i = tid; i < Ww * Nn; i += 256) memT[i] = EPSf;
    for (int i = 0; i < Nn; ++i) link[i * Nn + tid] = 0.f;
    s_usage[tid] = 0.f; s_ww[tid] = 0.f; s_prec[tid] = 0.f;
    s_rw[tid][0] = 0.f; s_rw[tid][1] = 0.f; s_rw[tid][2] = 0.f; s_rw[tid][3] = 0.f;
    ((float*)s_rvec)[tid] = 0.f;   // W*R == 256
    __syncthreads();

    const float4* rw4 = (const float4*)s_rw;

    for (int t = 0; t < Tt; ++t) {
        // ---- 1. ctrl_in = [x_t, rvec.flatten(w,r)] ----
        if (tid < INd) s_ctrl[tid] = x[(t * Bb + b) * INd + tid];
        s_ctrl[INd + tid] = ((const float*)s_rvec)[tid];
        __syncthreads();

        // ---- 2. h = tanh(ctrl @ W1 + b1) ----
        {
            float a0 = 0.f, a1 = 0.f, a2 = 0.f, a3 = 0.f;
#pragma unroll 4
            for (int i = 0; i < INDIM; i += 4) {
                a0 = fmaf(s_ctrl[i + 0], W1[(i + 0) * NH + tid], a0);
                a1 = fmaf(s_ctrl[i + 1], W1[(i + 1) * NH + tid], a1);
                a2 = fmaf(s_ctrl[i + 2], W1[(i + 2) * NH + tid], a2);
                a3 = fmaf(s_ctrl[i + 3], W1[(i + 3) * NH + tid], a3);
            }
            s_h[tid] = tanhf(b1[tid] + ((a0 + a1) + (a2 + a3)));
        }
        __syncthreads();

        // ---- 3. nn_out = tanh(h @ W2 + b2) ----
        {
            float a0 = 0.f, a1 = 0.f, a2 = 0.f, a3 = 0.f;
#pragma unroll 4
            for (int i = 0; i < NH; i += 4) {
                a0 = fmaf(s_h[i + 0], W2[(i + 0) * NO + tid], a0);
                a1 = fmaf(s_h[i + 1], W2[(i + 1) * NO + tid], a1);
                a2 = fmaf(s_h[i + 2], W2[(i + 2) * NO + tid], a2);
                a3 = fmaf(s_h[i + 3], W2[(i + 3) * NO + tid], a3);
            }
            s_nn[tid] = tanhf(b2[tid] + ((a0 + a1) + (a2 + a3)));
        }
        __syncthreads();

        // ---- 4. z = nn_out @ W_if + b_if  (471 outputs, 2 passes) ----
        for (int k = tid; k < IFS; k += 256) {
            float a0 = 0.f, a1 = 0.f, a2 = 0.f, a3 = 0.f;
#pragma unroll 4
            for (int i = 0; i < NO; i += 4) {
                a0 = fmaf(s_nn[i + 0], Wif[(i + 0) * IFS + k], a0);
                a1 = fmaf(s_nn[i + 1], Wif[(i + 1) * IFS + k], a1);
                a2 = fmaf(s_nn[i + 2], Wif[(i + 2) * IFS + k], a2);
                a3 = fmaf(s_nn[i + 3], Wif[(i + 3) * IFS + k], a3);
            }
            s_z[k] = bif[k] + ((a0 + a1) + (a2 + a3));
        }
        __syncthreads();

        // ---- 5. parse interface ----
        // offsets: rkeys 0..255 (w*4+r), rstr 256..259, wkey 260..323, wstr 324,
        // erase 325..388, wvec 389..452, fg 453..456, agate 457, wgate 458, rmodes 459..470
        if (tid < Rr) {
            float ss = 0.f;
            for (int w = 0; w < Ww; ++w) { float v = s_z[w * Rr + tid]; ss = fmaf(v, v, ss); }
            s_knorm[tid] = sqrtf(ss) + EPSf;
            s_rstr[tid] = oneplus_(s_z[256 + tid]);
            s_fg[tid] = sigm(s_z[453 + tid]);
            float a = s_z[459 + tid], bm = s_z[463 + tid], c = s_z[467 + tid];
            float mx = fmaxf(a, fmaxf(bm, c));
            float ea = expf(a - mx), eb = expf(bm - mx), ec = expf(c - mx);
            float inv = 1.f / ((ea + eb) + ec);
            s_rmode[0][tid] = ea * inv; s_rmode[1][tid] = eb * inv; s_rmode[2][tid] = ec * inv;
        } else if (tid == 8) {
            float ss = 0.f;
            for (int w = 0; w < Ww; ++w) { float v = s_z[260 + w]; ss = fmaf(v, v, ss); }
            s_sc[3] = sqrtf(ss) + EPSf;
        } else if (tid == 16) {
            s_sc[0] = oneplus_(s_z[324]);
            s_sc[1] = sigm(s_z[457]);
            s_sc[2] = sigm(s_z[458]);
        }
        __syncthreads();
        ((float*)s_rkeyn)[tid] = s_z[tid] / s_knorm[tid & 3];
        if (tid < Ww) {
            s_wkeyn[tid] = s_z[260 + tid] / s_sc[3];
            s_erase[tid] = sigm(s_z[325 + tid]);
            s_wvec[tid] = s_z[389 + tid];
        }
        __syncthreads();

        // ---- 6. retention & usage (OLD ww, OLD rw) ----
        {
            float ret = 1.f;
#pragma unroll
            for (int r = 0; r < Rr; ++r) ret *= 1.f - s_fg[r] * s_rw[tid][r];
            float u = s_usage[tid], wwo = s_ww[tid];
            u = (u + wwo - u * wwo) * ret;
            s_usage[tid] = u;
            s_skey[tid] = u;
            s_sidx[tid] = tid;
        }
        __syncthreads();

        // ---- 7. stable ascending argsort via bitonic on (key, idx) ----
        for (int k = 2; k <= Nn; k <<= 1) {
            for (int j = k >> 1; j > 0; j >>= 1) {
                int ixj = tid ^ j;
                if (ixj > tid) {
                    bool up = ((tid & k) == 0);
                    float k0 = s_skey[tid], k1 = s_skey[ixj];
                    int i0 = s_sidx[tid], i1 = s_sidx[ixj];
                    bool gt = (k0 > k1) || (k0 == k1 && i0 > i1);
                    if (gt == up) {
                        s_skey[tid] = k1; s_skey[ixj] = k0;
                        s_sidx[tid] = i1; s_sidx[ixj] = i0;
                    }
                }
                __syncthreads();
            }
        }

        // ---- 8. allocation weights ----
        s_cp[tid] = s_skey[tid];
        __syncthreads();
        for (int off = 1; off < Nn; off <<= 1) {
            float v = (tid >= off) ? s_cp[tid - off] : 1.f;
            __syncthreads();
            s_cp[tid] *= v;
            __syncthreads();
        }
        {
            float excl = (tid == 0) ? 1.f : s_cp[tid - 1];
            s_alloc[s_sidx[tid]] = (1.f - s_skey[tid]) * excl;
        }
        __syncthreads();

        // ---- 9. write content address (OLD mem; thread owns column n=tid) ----
        float wc_val;
        {
            float ss = 0.f, dot = 0.f;
#pragma unroll 4
            for (int w = 0; w < Ww; ++w) {
                float m = memT[w * Nn + tid];
                ss = fmaf(m, m, ss);
                dot = fmaf(m, s_wkeyn[w], dot);
            }
            float sim = dot / (sqrtf(ss) + EPSf) * s_sc[0];
            float mx = bmax(sim, s_red, tid);
            float e = expf(sim - mx);
            float sm = bsum(e, s_red, tid);
            wc_val = e / sm;
        }

        // ---- 10. write weights + sum(ww) ----
        float wwsum;
        {
            float ag = s_sc[1], wg = s_sc[2];
            float wwn = wg * (ag * s_alloc[tid] + (1.f - ag) * wc_val);
            s_ww[tid] = wwn;
            wwsum = bsum(wwn, s_red, tid);
        }
        __syncthreads();

        // ---- 11. mem update (own column) ----
        {
            float wwn = s_ww[tid];
#pragma unroll 4
            for (int w = 0; w < Ww; ++w) {
                float m = memT[w * Nn + tid];
                memT[w * Nn + tid] = m * (1.f - wwn * s_erase[w]) + wwn * s_wvec[w];
            }
        }

        // ---- 12. link update fused with bwd = link_new^T @ rw_old (own column) ----
        float bw0 = 0.f, bw1 = 0.f, bw2 = 0.f, bw3 = 0.f;
        {
            float wwt = s_ww[tid], pt = s_prec[tid];
#pragma unroll 2
            for (int k = 0; k < Nn; ++k) {
                float lold = link[k * Nn + tid];
                float lnew = (1.f - s_ww[k] - wwt) * lold + s_ww[k] * pt;
                if (k == tid) lnew = 0.f;
                link[k * Nn + tid] = lnew;
                float4 rwk = rw4[k];
                bw0 = fmaf(lnew, rwk.x, bw0);
                bw1 = fmaf(lnew, rwk.y, bw1);
                bw2 = fmaf(lnew, rwk.z, bw2);
                bw3 = fmaf(lnew, rwk.w, bw3);
            }
            // precedence update (own element; only self reads s_prec[tid])
            s_prec[tid] = (1.f - wwsum) * pt + wwt;
        }
        __syncthreads();

        // ---- 13. fwd = link_new @ rw_old (own row, float4) ----
        float fw0 = 0.f, fw1 = 0.f, fw2 = 0.f, fw3 = 0.f;
        {
            const float4* lrow = (const float4*)(link + (size_t)tid * Nn);
#pragma unroll 4
            for (int m4 = 0; m4 < Nn / 4; ++m4) {
                float4 l = lrow[m4];
                float4 w0 = rw4[m4 * 4 + 0], w1 = rw4[m4 * 4 + 1];
                float4 w2 = rw4[m4 * 4 + 2], w3 = rw4[m4 * 4 + 3];
                fw0 = fmaf(l.x, w0.x, fw0); fw1 = fmaf(l.x, w0.y, fw1);
                fw2 = fmaf(l.x, w0.z, fw2); fw3 = fmaf(l.x, w0.w, fw3);
                fw0 = fmaf(l.y, w1.x, fw0); fw1 = fmaf(l.y, w1.y, fw1);
                fw2 = fmaf(l.y, w1.z, fw2); fw3 = fmaf(l.y, w1.w, fw3);
                fw0 = fmaf(l.z, w2.x, fw0); fw1 = fmaf(l.z, w2.y, fw1);
                fw2 = fmaf(l.z, w2.z, fw2); fw3 = fmaf(l.z, w2.w, fw3);
                fw0 = fmaf(l.w, w3.x, fw0); fw1 = fmaf(l.w, w3.y, fw1);
                fw2 = fmaf(l.w, w3.z, fw2); fw3 = fmaf(l.w, w3.w, fw3);
            }
        }

        // ---- 14. read content address (NEW mem, own column) ----
        float4 rc;
        {
            float ss = 0.f, d0 = 0.f, d1 = 0.f, d2 = 0.f, d3 = 0.f;
#pragma unroll 4
            for (int w = 0; w < Ww; ++w) {
                float m = memT[w * Nn + tid];
                ss = fmaf(m, m, ss);
                d0 = fmaf(m, s_rkeyn[w][0], d0);
                d1 = fmaf(m, s_rkeyn[w][1], d1);
                d2 = fmaf(m, s_rkeyn[w][2], d2);
                d3 = fmaf(m, s_rkeyn[w][3], d3);
            }
            float den = sqrtf(ss) + EPSf;
            float4 sim;
            sim.x = d0 / den * s_rstr[0];
            sim.y = d1 / den * s_rstr[1];
            sim.z = d2 / den * s_rstr[2];
            sim.w = d3 / den * s_rstr[3];
            float4 mx = bmax4(sim, s_red, tid);
            float4 e;
            e.x = expf(sim.x - mx.x); e.y = expf(sim.y - mx.y);
            e.z = expf(sim.z - mx.z); e.w = expf(sim.w - mx.w);
            float4 sm = bsum4(e, s_red, tid);
            rc.x = e.x / sm.x; rc.y = e.y / sm.y; rc.z = e.z / sm.z; rc.w = e.w / sm.w;
        }

        // ---- 15. rw_new = bwd*m0 + rc*m1 + fwd*m2 ----
        __syncthreads();   // everyone done reading old rw
        s_rw[tid][0] = bw0 * s_rmode[0][0] + rc.x * s_rmode[1][0] + fw0 * s_rmode[2][0];
        s_rw[tid][1] = bw1 * s_rmode[0][1] + rc.y * s_rmode[1][1] + fw1 * s_rmode[2][1];
        s_rw[tid][2] = bw2 * s_rmode[0][2] + rc.z * s_rmode[1][2] + fw2 * s_rmode[2][2];
        s_rw[tid][3] = bw3 * s_rmode[0][3] + rc.w * s_rmode[1][3] + fw3 * s_rmode[2][3];
        __syncthreads();

        // ---- 16. rvec[w][r] = sum_n memT[w][n] * rw[n][r] ----
        {
            int w = tid >> 2, r = tid & 3;
            float a0 = 0.f, a1 = 0.f;
#pragma unroll 4
            for (int n = 0; n < Nn; n += 2) {
                a0 = fmaf(memT[w * Nn + n], s_rw[n][r], a0);
                a1 = fmaf(memT[w * Nn + n + 1], s_rw[n + 1][r], a1);
            }
            ((float*)s_rvec)[tid] = a0 + a1;
        }
        __syncthreads();

        // ---- 17. out = nn_out @ W_out + rvec_flat @ W_mem_out ----
        {
            int j = tid & 63, p = tid >> 6;   // p uniform per wave
            float acc = 0.f;
            if (p < 2) {
                int base = p * 128;
#pragma unroll 4
                for (int i = 0; i < 128; ++i)
                    acc = fmaf(s_nn[base + i], Wout[(base + i) * OUTd + j], acc);
            } else {
                int base = (p - 2) * 128;
#pragma unroll 4
                for (int i = 0; i < 128; ++i)
                    acc = fmaf(((const float*)s_rvec)[base + i], Wmem[(base + i) * OUTd + j], acc);
            }
            s_outp[p][j] = acc;
        }
        __syncthreads();
        if (tid < OUTd)
            out[(t * Bb + b) * OUTd + tid] =
                (s_outp[0][tid] + s_outp[1][tid]) + (s_outp[2][tid] + s_outp[3][tid]);
        __syncthreads();
    }
}

extern "C" void kernel_launch(void* const* d_in, const int* in_sizes, int n_in,
                              void* d_out, int out_size, void* d_ws, size_t ws_size,
                              hipStream_t stream) {
    const float* x    = (const float*)d_in[0];
    const float* W1   = (const float*)d_in[1];
    const float* b1   = (const float*)d_in[2];
    const float* W2   = (const float*)d_in[3];
    const float* b2   = (const float*)d_in[4];
    const float* Wif  = (const float*)d_in[5];
    const float* bif  = (const float*)d_in[6];
    const float* Wout = (const float*)d_in[7];
    const float* Wmem = (const float*)d_in[8];
    float* out = (float*)d_out;
    float* ws = (float*)d_ws;   // needs 16*(64*256 + 256*256)*4 = 5.25 MB

    dnc_kernel<<<dim3(Bb), dim3(256), 0, stream>>>(
        x, W1, b1, W2, b2, Wif, bif, Wout, Wmem, out, ws);
}

// Round 2
// 4304.935 us; speedup vs baseline: 1.1486x; 1.1486x over previous
//
#include <hip/hip_runtime.h>
#include <math.h>

#define Tt 64
#define Bb 16
#define Nn 256
#define Ww 64
#define Rr 4
#define INd 64
#define OUTd 64
#define IFS 471
#define EPSf 1e-6f

__device__ __forceinline__ float sigm(float x) { return 1.f / (1.f + expf(-x)); }
// jax.nn.softplus(x) = max(x,0) + log1p(exp(-|x|)); oneplus = 1 + softplus
__device__ __forceinline__ float oneplus_(float x) {
    return 1.f + fmaxf(x, 0.f) + log1pf(expf(-fabsf(x)));
}

// One block (1024 threads, 16 waves) per batch element; whole T=64 scan inside.
__global__ __launch_bounds__(1024) void dnc_kernel(
    const float* __restrict__ x,     // (T,B,64)
    const float* __restrict__ W1,    // (320,256)
    const float* __restrict__ b1,    // (256)
    const float* __restrict__ W2,    // (256,256)
    const float* __restrict__ b2,    // (256)
    const float* __restrict__ Wif,   // (256,471)
    const float* __restrict__ bif,   // (471)
    const float* __restrict__ Wout,  // (256,64)
    const float* __restrict__ Wmem,  // (256,64)
    float* __restrict__ out,         // (T,B,64)
    float* __restrict__ ws)
{
    const int b = blockIdx.x;
    const int tid = threadIdx.x;
    const int lane = tid & 63;
    const int wv = tid >> 6;          // wave 0..15
    const int q = tid >> 8;           // quarter 0..3
    const int n8 = tid & 255;         // 0..255
    const int rr = q;                 // r-group for (r,n) layouts

    float* memT = ws + (size_t)b * (Ww * Nn);                         // [w][n]
    float* link = ws + (size_t)Bb * (Ww * Nn) + (size_t)b * (Nn * Nn); // [n][m]

    __shared__ float s_lp[4][256][5];   // padded partials (bw/fw/rc dots)
    __shared__ float s_ssp[4][256];     // ss / rank partials
    __shared__ float s_part[1024];      // GEMV partials
    __shared__ float s_ctrl[320];
    __shared__ float s_h[256];
    __shared__ float s_nn[256];
    __shared__ float s_z[472];
    __shared__ float s_usage[256], s_ww[256], s_prec[256];
    __shared__ float s_sorted[256], s_cp[256];
    __shared__ int   s_rank[256];
    __shared__ float s_rw[256][4];
    __shared__ float s_rvec[256];       // [w][r] flat w*4+r
    __shared__ float s_rkeyn[256];      // [w][r] flat w*4+r
    __shared__ float s_wkeyn[64], s_erase[64], s_wvec[64];
    __shared__ float s_fg[4], s_rstr[4], s_knorm[4], s_rmode[3][4], s_sc[4];
    __shared__ float s_red[32];

    // ---- init state (ws is poisoned before every launch) ----
    for (int i = tid; i < Ww * Nn; i += 1024) memT[i] = EPSf;
    for (int i = tid; i < Nn * Nn; i += 1024) link[i] = 0.f;
    if (tid < 256) {
        s_usage[tid] = 0.f; s_ww[tid] = 0.f; s_prec[tid] = 0.f; s_rvec[tid] = 0.f;
        s_rw[tid][0] = 0.f; s_rw[tid][1] = 0.f; s_rw[tid][2] = 0.f; s_rw[tid][3] = 0.f;
    }
    if (tid < 64) s_ctrl[tid] = x[b * INd + tid];
    else if (tid < 320) s_ctrl[tid] = 0.f;

    const float4* rw4 = (const float4*)s_rw;

    for (int t = 0; t < Tt; ++t) {
        __syncthreads();

        // ---- GEMV1: h = tanh(ctrl(320) @ W1 + b1), K-split 4 ----
        {
            int kb = q * 80;
            float a0=0,a1=0,a2=0,a3=0,a4=0,a5=0,a6=0,a7=0;
#pragma unroll 2
            for (int kk = 0; kk < 80; kk += 8) {
                int k = kb + kk;
                a0 = fmaf(s_ctrl[k+0], W1[(k+0)*256 + n8], a0);
                a1 = fmaf(s_ctrl[k+1], W1[(k+1)*256 + n8], a1);
                a2 = fmaf(s_ctrl[k+2], W1[(k+2)*256 + n8], a2);
                a3 = fmaf(s_ctrl[k+3], W1[(k+3)*256 + n8], a3);
                a4 = fmaf(s_ctrl[k+4], W1[(k+4)*256 + n8], a4);
                a5 = fmaf(s_ctrl[k+5], W1[(k+5)*256 + n8], a5);
                a6 = fmaf(s_ctrl[k+6], W1[(k+6)*256 + n8], a6);
                a7 = fmaf(s_ctrl[k+7], W1[(k+7)*256 + n8], a7);
            }
            s_part[q*256 + n8] = ((a0+a1)+(a2+a3)) + ((a4+a5)+(a6+a7));
        }
        __syncthreads();
        if (tid < 256)
            s_h[tid] = tanhf(b1[tid] + ((s_part[tid]+s_part[256+tid])+(s_part[512+tid]+s_part[768+tid])));
        __syncthreads();

        // ---- GEMV2: nn = tanh(h @ W2 + b2), K-split 4 ----
        {
            int kb = q * 64;
            float a0=0,a1=0,a2=0,a3=0,a4=0,a5=0,a6=0,a7=0;
#pragma unroll 2
            for (int kk = 0; kk < 64; kk += 8) {
                int k = kb + kk;
                a0 = fmaf(s_h[k+0], W2[(k+0)*256 + n8], a0);
                a1 = fmaf(s_h[k+1], W2[(k+1)*256 + n8], a1);
                a2 = fmaf(s_h[k+2], W2[(k+2)*256 + n8], a2);
                a3 = fmaf(s_h[k+3], W2[(k+3)*256 + n8], a3);
                a4 = fmaf(s_h[k+4], W2[(k+4)*256 + n8], a4);
                a5 = fmaf(s_h[k+5], W2[(k+5)*256 + n8], a5);
                a6 = fmaf(s_h[k+6], W2[(k+6)*256 + n8], a6);
                a7 = fmaf(s_h[k+7], W2[(k+7)*256 + n8], a7);
            }
            s_part[q*256 + n8] = ((a0+a1)+(a2+a3)) + ((a4+a5)+(a6+a7));
        }
        __syncthreads();
        if (tid < 256)
            s_nn[tid] = tanhf(b2[tid] + ((s_part[tid]+s_part[256+tid])+(s_part[512+tid]+s_part[768+tid])));
        __syncthreads();

        // ---- GEMV3: z = nn @ W_if + b_if (471 cols), K-split 2 ----
        {
            int o = tid & 511, h2 = tid >> 9;
            if (o < IFS) {
                int kb = h2 * 128;
                float a0=0,a1=0,a2=0,a3=0,a4=0,a5=0,a6=0,a7=0;
#pragma unroll 2
                for (int kk = 0; kk < 128; kk += 8) {
                    int k = kb + kk;
                    a0 = fmaf(s_nn[k+0], Wif[(k+0)*IFS + o], a0);
                    a1 = fmaf(s_nn[k+1], Wif[(k+1)*IFS + o], a1);
                    a2 = fmaf(s_nn[k+2], Wif[(k+2)*IFS + o], a2);
                    a3 = fmaf(s_nn[k+3], Wif[(k+3)*IFS + o], a3);
                    a4 = fmaf(s_nn[k+4], Wif[(k+4)*IFS + o], a4);
                    a5 = fmaf(s_nn[k+5], Wif[(k+5)*IFS + o], a5);
                    a6 = fmaf(s_nn[k+6], Wif[(k+6)*IFS + o], a6);
                    a7 = fmaf(s_nn[k+7], Wif[(k+7)*IFS + o], a7);
                }
                s_part[h2*512 + o] = ((a0+a1)+(a2+a3)) + ((a4+a5)+(a6+a7));
            }
        }
        __syncthreads();
        if (tid < IFS) s_z[tid] = bif[tid] + s_part[tid] + s_part[512 + tid];
        __syncthreads();

        // ---- parse interface: scalars ----
        // rkeys 0..255 (w*4+r), rstr 256..259, wkey 260..323, wstr 324,
        // erase 325..388, wvec 389..452, fg 453..456, agate 457, wgate 458, rmodes 459..470
        if (tid < Rr) {
            float ss = 0.f;
            for (int w = 0; w < Ww; ++w) { float v = s_z[w*Rr + tid]; ss = fmaf(v, v, ss); }
            s_knorm[tid] = sqrtf(ss) + EPSf;
            s_rstr[tid] = oneplus_(s_z[256 + tid]);
            s_fg[tid] = sigm(s_z[453 + tid]);
            float a = s_z[459 + tid], bm = s_z[463 + tid], c = s_z[467 + tid];
            float mx = fmaxf(a, fmaxf(bm, c));
            float ea = expf(a - mx), eb = expf(bm - mx), ec = expf(c - mx);
            float inv = 1.f / ((ea + eb) + ec);
            s_rmode[0][tid] = ea * inv; s_rmode[1][tid] = eb * inv; s_rmode[2][tid] = ec * inv;
        } else if (tid == 8) {
            float ss = 0.f;
            for (int w = 0; w < Ww; ++w) { float v = s_z[260 + w]; ss = fmaf(v, v, ss); }
            s_sc[3] = sqrtf(ss) + EPSf;
        } else if (tid == 16) {
            s_sc[0] = oneplus_(s_z[324]);
            s_sc[1] = sigm(s_z[457]);
            s_sc[2] = sigm(s_z[458]);
        }
        __syncthreads();

        // ---- parse vectors + usage update (OLD ww, OLD rw) ----
        if (tid < 256) {
            s_rkeyn[tid] = s_z[tid] / s_knorm[tid & 3];
            float ret = 1.f;
#pragma unroll
            for (int r = 0; r < Rr; ++r) ret *= 1.f - s_fg[r] * s_rw[tid][r];
            float u = s_usage[tid], wwo = s_ww[tid];
            s_usage[tid] = (u + wwo - u * wwo) * ret;
        }
        if (tid < Ww) {
            s_wkeyn[tid] = s_z[260 + tid] / s_sc[3];
            s_erase[tid] = sigm(s_z[325 + tid]);
            s_wvec[tid]  = s_z[389 + tid];
        }
        __syncthreads();

        // ---- rank-based stable argsort: rank partials ----
        {
            float ui = s_usage[n8];
            float cnt = 0.f;
            int j0 = q * 64;
#pragma unroll 8
            for (int j = j0; j < j0 + 64; ++j) {
                float uj = s_usage[j];
                if (uj < ui || (uj == ui && j < n8)) cnt += 1.f;
            }
            s_ssp[q][n8] = cnt;
        }
        __syncthreads();
        if (tid < 256) {
            int rk = (int)(s_ssp[0][tid] + s_ssp[1][tid] + s_ssp[2][tid] + s_ssp[3][tid] + 0.5f);
            s_rank[tid] = rk;
            s_sorted[rk] = s_usage[tid];
        }
        __syncthreads();

        // ---- exclusive prefix product over sorted usage (wave 0, in-register) ----
        if (wv == 0) {
            float4 v = ((const float4*)s_sorted)[lane];
            float p1 = v.x * v.y, p2 = p1 * v.z, tot = p2 * v.w;
            float incl = tot;
#pragma unroll
            for (int off = 1; off < 64; off <<= 1) {
                float tvv = __shfl_up(incl, off, 64);
                if (lane >= off) incl *= tvv;
            }
            float excl = __shfl_up(incl, 1, 64);
            if (lane == 0) excl = 1.f;
            float4 o;
            o.x = excl; o.y = excl * v.x; o.z = excl * p1; o.w = excl * p2;
            ((float4*)s_cp)[lane] = o;
        }
        __syncthreads();

        // ---- write content address partials (OLD mem) ----
        {
            float ssv = 0.f, dot = 0.f;
            int w0 = q * 16;
#pragma unroll
            for (int w = w0; w < w0 + 16; ++w) {
                float m = memT[w*256 + n8];
                ssv = fmaf(m, m, ssv);
                dot = fmaf(m, s_wkeyn[w], dot);
            }
            s_lp[q][n8][0] = dot;
            s_ssp[q][n8] = ssv;
        }
        __syncthreads();

        // ---- wc softmax + alloc + write weights ----
        float simwc = 0.f, ewc = 0.f, wwsum = 0.f;
        if (tid < 256) {
            float dot = s_lp[0][tid][0] + s_lp[1][tid][0] + s_lp[2][tid][0] + s_lp[3][tid][0];
            float ssv = s_ssp[0][tid] + s_ssp[1][tid] + s_ssp[2][tid] + s_ssp[3][tid];
            simwc = dot / (sqrtf(ssv) + EPSf) * s_sc[0];
            float m = simwc;
#pragma unroll
            for (int o = 32; o; o >>= 1) m = fmaxf(m, __shfl_xor(m, o, 64));
            if (lane == 0) s_red[wv] = m;
        }
        __syncthreads();
        if (tid < 256) {
            float m = fmaxf(fmaxf(s_red[0], s_red[1]), fmaxf(s_red[2], s_red[3]));
            ewc = expf(simwc - m);
            float s = ewc;
#pragma unroll
            for (int o = 32; o; o >>= 1) s += __shfl_xor(s, o, 64);
            if (lane == 0) s_red[4 + wv] = s;
        }
        __syncthreads();
        if (tid < 256) {
            float sm = (s_red[4] + s_red[5]) + (s_red[6] + s_red[7]);
            float wc = ewc / sm;
            float allocv = (1.f - s_usage[tid]) * s_cp[s_rank[tid]];
            float ag = s_sc[1], wg = s_sc[2];
            float wwn = wg * (ag * allocv + (1.f - ag) * wc);
            s_ww[tid] = wwn;
            float s = wwn;
#pragma unroll
            for (int o = 32; o; o >>= 1) s += __shfl_xor(s, o, 64);
            if (lane == 0) s_red[8 + wv] = s;
        }
        __syncthreads();
        wwsum = (s_red[8] + s_red[9]) + (s_red[10] + s_red[11]);

        // ---- mem update + link update fused with bwd partials ----
#pragma unroll
        for (int j = 0; j < 4; ++j) {
            int i = tid + j * 4096;   // covers 16384
            int w = i >> 8, n = i & 255;
            float m0 = memT[i];
            memT[i] = m0 * (1.f - s_ww[n] * s_erase[w]) + s_ww[n] * s_wvec[w];
        }
        {
            float pt = s_prec[n8], wwc = s_ww[n8];
            float b0 = 0.f, b1_ = 0.f, b2_ = 0.f, b3_ = 0.f;
            int k0 = q * 64;
#pragma unroll 8
            for (int k = k0; k < k0 + 64; ++k) {
                float lold = link[k*256 + n8];
                float wk = s_ww[k];
                float lnew = (1.f - wk - wwc) * lold + wk * pt;
                if (k == n8) lnew = 0.f;
                link[k*256 + n8] = lnew;
                float4 r4 = rw4[k];
                b0  = fmaf(lnew, r4.x, b0);
                b1_ = fmaf(lnew, r4.y, b1_);
                b2_ = fmaf(lnew, r4.z, b2_);
                b3_ = fmaf(lnew, r4.w, b3_);
            }
            s_lp[q][n8][0] = b0; s_lp[q][n8][1] = b1_;
            s_lp[q][n8][2] = b2_; s_lp[q][n8][3] = b3_;
        }
        __syncthreads();

        // ---- reduce bwd (register, (r,n) layout) + precedence update ----
        float bwv = s_lp[0][n8][rr] + s_lp[1][n8][rr] + s_lp[2][n8][rr] + s_lp[3][n8][rr];
        if (tid < 256) s_prec[tid] = (1.f - wwsum) * s_prec[tid] + s_ww[tid];
        __syncthreads();

        // ---- fwd partials: link_new rows (float4) ----
        {
            float f0 = 0.f, f1 = 0.f, f2 = 0.f, f3 = 0.f;
            const float4* lrow = (const float4*)(link + n8*256 + q*64);
            int mb = q * 64;
#pragma unroll 8
            for (int m4 = 0; m4 < 16; ++m4) {
                float4 l = lrow[m4];
                float4 w0 = rw4[mb + m4*4 + 0], w1 = rw4[mb + m4*4 + 1];
                float4 w2 = rw4[mb + m4*4 + 2], w3 = rw4[mb + m4*4 + 3];
                f0 = fmaf(l.x, w0.x, f0); f1 = fmaf(l.x, w0.y, f1);
                f2 = fmaf(l.x, w0.z, f2); f3 = fmaf(l.x, w0.w, f3);
                f0 = fmaf(l.y, w1.x, f0); f1 = fmaf(l.y, w1.y, f1);
                f2 = fmaf(l.y, w1.z, f2); f3 = fmaf(l.y, w1.w, f3);
                f0 = fmaf(l.z, w2.x, f0); f1 = fmaf(l.z, w2.y, f1);
                f2 = fmaf(l.z, w2.z, f2); f3 = fmaf(l.z, w2.w, f3);
                f0 = fmaf(l.w, w3.x, f0); f1 = fmaf(l.w, w3.y, f1);
                f2 = fmaf(l.w, w3.z, f2); f3 = fmaf(l.w, w3.w, f3);
            }
            s_lp[q][n8][0] = f0; s_lp[q][n8][1] = f1;
            s_lp[q][n8][2] = f2; s_lp[q][n8][3] = f3;
        }
        __syncthreads();
        float fwv = s_lp[0][n8][rr] + s_lp[1][n8][rr] + s_lp[2][n8][rr] + s_lp[3][n8][rr];
        __syncthreads();

        // ---- read content partials (NEW mem) ----
        {
            float ssv = 0.f, d0 = 0.f, d1 = 0.f, d2 = 0.f, d3 = 0.f;
            int w0 = q * 16;
#pragma unroll
            for (int w = w0; w < w0 + 16; ++w) {
                float m = memT[w*256 + n8];
                float4 kk = *(const float4*)&s_rkeyn[w*4];
                ssv = fmaf(m, m, ssv);
                d0 = fmaf(m, kk.x, d0); d1 = fmaf(m, kk.y, d1);
                d2 = fmaf(m, kk.z, d2); d3 = fmaf(m, kk.w, d3);
            }
            s_lp[q][n8][0] = d0; s_lp[q][n8][1] = d1;
            s_lp[q][n8][2] = d2; s_lp[q][n8][3] = d3;
            s_ssp[q][n8] = ssv;
        }
        __syncthreads();

        // ---- rc softmax (4 parallel groups, r = rr) + rw_new ----
        {
            float dot = s_lp[0][n8][rr] + s_lp[1][n8][rr] + s_lp[2][n8][rr] + s_lp[3][n8][rr];
            float ssv = s_ssp[0][n8] + s_ssp[1][n8] + s_ssp[2][n8] + s_ssp[3][n8];
            float sim = dot / (sqrtf(ssv) + EPSf) * s_rstr[rr];
            float m = sim;
#pragma unroll
            for (int o = 32; o; o >>= 1) m = fmaxf(m, __shfl_xor(m, o, 64));
            if (lane == 0) s_red[wv] = m;
            __syncthreads();
            m = fmaxf(fmaxf(s_red[rr*4+0], s_red[rr*4+1]), fmaxf(s_red[rr*4+2], s_red[rr*4+3]));
            float e = expf(sim - m);
            float s = e;
#pragma unroll
            for (int o = 32; o; o >>= 1) s += __shfl_xor(s, o, 64);
            if (lane == 0) s_red[16 + wv] = s;
            __syncthreads();
            float sm = (s_red[16+rr*4+0] + s_red[16+rr*4+1]) + (s_red[16+rr*4+2] + s_red[16+rr*4+3]);
            float rc = e / sm;
            s_rw[n8][rr] = bwv * s_rmode[0][rr] + rc * s_rmode[1][rr] + fwv * s_rmode[2][rr];
        }
        __syncthreads();

        // ---- rvec[w][r] = sum_n mem[w][n]*rw[n][r], K-split 4 ----
        {
            int w = n8 >> 2, r = n8 & 3;
            float a = 0.f;
            int j0 = q * 64;
#pragma unroll 8
            for (int n = j0; n < j0 + 64; ++n)
                a = fmaf(memT[w*256 + n], s_rw[n][r], a);
            s_part[q*256 + n8] = a;
        }
        __syncthreads();
        if (tid < 256)
            s_rvec[tid] = (s_part[tid] + s_part[256+tid]) + (s_part[512+tid] + s_part[768+tid]);
        __syncthreads();

        // ---- out = nn @ W_out + rvec @ W_mem_out (16-way K-split) ----
        {
            float acc = 0.f;
            if (wv < 8) {
                int k0 = wv * 32;
#pragma unroll 8
                for (int k = k0; k < k0 + 32; ++k)
                    acc = fmaf(s_nn[k], Wout[k*64 + lane], acc);
            } else {
                int k0 = (wv - 8) * 32;
#pragma unroll 8
                for (int k = k0; k < k0 + 32; ++k)
                    acc = fmaf(s_rvec[k], Wmem[k*64 + lane], acc);
            }
            s_part[wv*64 + lane] = acc;
        }
        __syncthreads();
        if (tid < 64) {
            float s = 0.f;
#pragma unroll
            for (int g = 0; g < 16; ++g) s += s_part[g*64 + tid];
            out[(t*Bb + b)*OUTd + tid] = s;
        } else if (tid >= 64 && tid < 320) {
            s_ctrl[tid] = s_rvec[tid - 64];        // next-step controller input
        } else if (tid >= 384 && tid < 448) {
            if (t + 1 < Tt) s_ctrl[tid - 384] = x[((t+1)*Bb + b)*INd + (tid - 384)];
        }
        // loop-top __syncthreads covers the writes above
    }
}

extern "C" void kernel_launch(void* const* d_in, const int* in_sizes, int n_in,
                              void* d_out, int out_size, void* d_ws, size_t ws_size,
                              hipStream_t stream) {
    const float* x    = (const float*)d_in[0];
    const float* W1   = (const float*)d_in[1];
    const float* b1   = (const float*)d_in[2];
    const float* W2   = (const float*)d_in[3];
    const float* b2   = (const float*)d_in[4];
    const float* Wif  = (const float*)d_in[5];
    const float* bif  = (const float*)d_in[6];
    const float* Wout = (const float*)d_in[7];
    const float* Wmem = (const float*)d_in[8];
    float* out = (float*)d_out;
    float* ws = (float*)d_ws;   // 16*(64*256 + 256*256)*4 = 5.25 MB

    dnc_kernel<<<dim3(Bb), dim3(1024), 0, stream>>>(
        x, W1, b1, W2, b2, Wif, bif, Wout, Wmem, out, ws);
}